// Round 6
// baseline (122.190 us; speedup 1.0000x reference)
//
#include <hip/hip_runtime.h>
#include <math.h>

constexpr int B = 32, S = 4096, H = 512;
constexpr int BDIM = 256;            // 4 waves of 64
constexpr int MAX_SPLIT = 128;       // blocks per batch row-range split
constexpr float LOG2E = 1.44269504088896340736f;
constexpr float DEFER_THR = 11.5415603f;   // 8 nats in log2 domain

typedef float f4 __attribute__((ext_vector_type(4)));

// ---------------------------------------------------------------------------
// Kernel 1: u[b,k] = (sum_h h_t[b,h] * W[h,k]) * log2(e)   (tiny: 32x512)
// ---------------------------------------------------------------------------
__global__ __launch_bounds__(BDIM) void u_kernel(const float* __restrict__ h_t,
                                                 const float* __restrict__ W,
                                                 float* __restrict__ u) {
    const int b = blockIdx.y;
    const int k = blockIdx.x * BDIM + threadIdx.x;
    __shared__ float hs[H];
    for (int i = threadIdx.x; i < H; i += BDIM) hs[i] = h_t[b * H + i];
    __syncthreads();
    float a0 = 0.f, a1 = 0.f, a2 = 0.f, a3 = 0.f;
#pragma unroll 8
    for (int h = 0; h < H; h += 4) {
        a0 = fmaf(hs[h],     W[(size_t)(h)     * H + k], a0);
        a1 = fmaf(hs[h + 1], W[(size_t)(h + 1) * H + k], a1);
        a2 = fmaf(hs[h + 2], W[(size_t)(h + 2) * H + k], a2);
        a3 = fmaf(hs[h + 3], W[(size_t)(h + 3) * H + k], a3);
    }
    u[b * H + k] = ((a0 + a1) + (a2 + a3)) * LOG2E;
}

// ---------------------------------------------------------------------------
// Kernel 2: streaming pass, 32-lane row-groups.
// Wave processes 2 rows/iteration: group g = lane>>5 owns row r+g; lane
// j = lane&31 covers columns k*128 + j*4 (k=0..3, 4 x f4 = 16 floats).
// Reduce = 5 shfl steps per 2 rows (was 6 per row). Cross-group merge once
// at wave end via shfl_xor(32). ctx loads PLAIN (L3 retention), stores NT.
// ---------------------------------------------------------------------------
__global__ __launch_bounds__(BDIM) void flash_kernel(const float* __restrict__ ctx,
                                                     const float* __restrict__ u,
                                                     float* __restrict__ newbuf,
                                                     float* __restrict__ pacc,
                                                     float* __restrict__ pml,
                                                     int nsplit) {
    const int b     = blockIdx.y;
    const int split = blockIdx.x;
    const int w     = threadIdx.x >> 6;
    const int lane  = threadIdx.x & 63;
    const int g     = lane >> 5;         // row-group 0/1
    const int j     = lane & 31;         // column lane within group
    const int rpb   = S / nsplit;        // rows per block
    const int rpw   = rpb / 4;           // rows per wave
    const int s0    = split * rpb + w * rpw;

    // u fragment: cols k*128 + j*4  (same for both groups)
    const f4* ub = (const f4*)(u + (size_t)b * H);
    f4 uf[4];
#pragma unroll
    for (int k = 0; k < 4; ++k) uf[k] = ub[j + 32 * k];

    float m = -INFINITY, l = 0.f;
    f4 acc[4] = {{0,0,0,0},{0,0,0,0},{0,0,0,0},{0,0,0,0}};

#pragma unroll 2
    for (int r = 0; r < rpw; r += 2) {
        const size_t row = (size_t)b * S + s0 + r + g;
        const f4* crow = (const f4*)(ctx + row * H);
        f4 c[4];
#pragma unroll
        for (int k = 0; k < 4; ++k) c[k] = crow[j + 32 * k];

        f4* orow = (f4*)(newbuf + row * H);
#pragma unroll
        for (int k = 0; k < 4; ++k)
            __builtin_nontemporal_store(c[k], orow + j + 32 * k);

        float d = c[0].x * uf[0].x;
        d = fmaf(c[0].y, uf[0].y, d); d = fmaf(c[0].z, uf[0].z, d);
        d = fmaf(c[0].w, uf[0].w, d);
#pragma unroll
        for (int k = 1; k < 4; ++k) {
            d = fmaf(c[k].x, uf[k].x, d); d = fmaf(c[k].y, uf[k].y, d);
            d = fmaf(c[k].z, uf[k].z, d); d = fmaf(c[k].w, uf[k].w, d);
        }
        // reduce within the 32-lane group (bit 5 untouched)
#pragma unroll
        for (int off = 16; off >= 1; off >>= 1) d += __shfl_xor(d, off);

        if (d > m + DEFER_THR) {          // group-uniform, rare
            const float sc = exp2f(m - d);  // first time: exp2(-inf)=0
#pragma unroll
            for (int k = 0; k < 4; ++k) acc[k] *= sc;
            l *= sc; m = d;
        }
        const float p = exp2f(d - m);     // bounded by e^8
#pragma unroll
        for (int k = 0; k < 4; ++k) acc[k] += p * c[k];
        l += p;
    }

    // ---- merge the two 32-lane groups inside the wave ----
    const float mo = __shfl_xor(m, 32);
    const float lo = __shfl_xor(l, 32);
    const float M  = fmaxf(m, mo);
    const float es = exp2f(m - M), eo = exp2f(mo - M);
    const float lw = es * l + eo * lo;
    f4 am[4];
#pragma unroll
    for (int k = 0; k < 4; ++k) {
        f4 other;
        other.x = __shfl_xor(acc[k].x, 32);
        other.y = __shfl_xor(acc[k].y, 32);
        other.z = __shfl_xor(acc[k].z, 32);
        other.w = __shfl_xor(acc[k].w, 32);
        am[k] = es * acc[k] + eo * other;
    }

    // ---- block-level reduce of 4 wave partials via LDS ----
    __shared__ float lacc[4][H];
    __shared__ float lml[4][2];
    if (g == 0) {
        f4* dst = (f4*)&lacc[w][0];
#pragma unroll
        for (int k = 0; k < 4; ++k) dst[j + 32 * k] = am[k];
        if (j == 0) { lml[w][0] = M; lml[w][1] = lw; }
    }
    __syncthreads();

    const float m0 = lml[0][0], m1 = lml[1][0], m2 = lml[2][0], m3 = lml[3][0];
    const float Mb = fmaxf(fmaxf(m0, m1), fmaxf(m2, m3));
    const float e0 = exp2f(m0 - Mb), e1 = exp2f(m1 - Mb);
    const float e2 = exp2f(m2 - Mb), e3 = exp2f(m3 - Mb);

    const int t    = threadIdx.x;
    const int pidx = b * nsplit + split;
    const float ca = e0 * lacc[0][t]       + e1 * lacc[1][t]
                   + e2 * lacc[2][t]       + e3 * lacc[3][t];
    const float cb = e0 * lacc[0][256 + t] + e1 * lacc[1][256 + t]
                   + e2 * lacc[2][256 + t] + e3 * lacc[3][256 + t];
    pacc[(size_t)pidx * H + t]       = ca;
    pacc[(size_t)pidx * H + 256 + t] = cb;
    if (t == 0) {
        const float L = e0 * lml[0][1] + e1 * lml[1][1]
                      + e2 * lml[2][1] + e3 * lml[3][1];
        pml[2 * pidx] = Mb; pml[2 * pidx + 1] = L;
    }
}

// ---------------------------------------------------------------------------
// Kernel 3: combine per-block partials -> cntx[b,:]; also writes the cyclic-
// buffer row: newbuf[b,pos,:] = h_t[b,:] (ordered after flash).  grid=(B,2).
// ---------------------------------------------------------------------------
__global__ __launch_bounds__(BDIM) void combine_kernel(const float* __restrict__ pacc,
                                                       const float* __restrict__ pml,
                                                       const float* __restrict__ h_t,
                                                       const int* __restrict__ posp,
                                                       float* __restrict__ newbuf,
                                                       float* __restrict__ cntx,
                                                       int nsplit) {
    const int b    = blockIdx.x;
    const int half = blockIdx.y;
    const int t    = threadIdx.x;
    const int col  = half * 256 + t;

    int pos = posp[0] % S; if (pos < 0) pos += S;
    newbuf[((size_t)b * S + pos) * H + col] = h_t[b * H + col];

    __shared__ float lm[MAX_SPLIT], ll[MAX_SPLIT];
    for (int p = t; p < nsplit; p += BDIM) {
        lm[p] = pml[2 * (b * nsplit + p)];
        ll[p] = pml[2 * (b * nsplit + p) + 1];
    }
    __syncthreads();

    float M = -INFINITY;
    for (int p = 0; p < nsplit; ++p) M = fmaxf(M, lm[p]);

    float acc = 0.f, L = 0.f;
#pragma unroll 4
    for (int p = 0; p < nsplit; ++p) {
        const float e = exp2f(lm[p] - M);
        L   = fmaf(e, ll[p], L);
        acc = fmaf(e, pacc[(size_t)(b * nsplit + p) * H + col], acc);
    }
    cntx[b * H + col] = acc / L;
}

// ---------------------------------------------------------------------------
extern "C" void kernel_launch(void* const* d_in, const int* in_sizes, int n_in,
                              void* d_out, int out_size, void* d_ws, size_t ws_size,
                              hipStream_t stream) {
    const float* h_t = (const float*)d_in[0];
    const float* ctx = (const float*)d_in[1];
    const float* W   = (const float*)d_in[2];
    const int*   pos = (const int*)d_in[3];

    float* out    = (float*)d_out;
    float* cntx   = out;                     // [B,H]
    float* newbuf = out + (size_t)B * H;     // [B,S,H]

    // workspace layout: u [B*H] | pacc [B*nsplit*H] | pml [B*nsplit*2]
    char*  ws = (char*)d_ws;
    float* u  = (float*)ws;
    const size_t u_bytes = (size_t)B * H * sizeof(float);

    int nsplit = MAX_SPLIT;
    while (nsplit > 1) {
        const size_t need = u_bytes
                          + (size_t)B * nsplit * H * sizeof(float)
                          + (size_t)B * nsplit * 2 * sizeof(float);
        if (need <= ws_size) break;
        nsplit >>= 1;
    }
    float* pacc = (float*)(ws + u_bytes);
    float* pml  = pacc + (size_t)B * nsplit * H;

    u_kernel<<<dim3(H / BDIM, B), BDIM, 0, stream>>>(h_t, W, u);
    flash_kernel<<<dim3(nsplit, B), BDIM, 0, stream>>>(ctx, u, newbuf,
                                                       pacc, pml, nsplit);
    combine_kernel<<<dim3(B, 2), BDIM, 0, stream>>>(pacc, pml, h_t, pos,
                                                    newbuf, cntx, nsplit);
}